// Round 1
// baseline (184.158 us; speedup 1.0000x reference)
//
#include <hip/hip_runtime.h>

// irreps: x1 = 128x0e + 128x1o (512), x2 = 1x0e + 1x1o (4), w = 5*128 (640)
// out = 128x0e + 128x1o (512). All fp32. Pure memory-bound elementwise-ish op.
//
// Per edge z, channel u:
//   s = x1[z,u]; v = x1[z,128+3u .. +3); a = x2[z,0]; b = x2[z,1..4)
//   out[z,u]            = s*a*w0[u] + (1/sqrt3)*(v.b)*w3[u]
//   out[z,128+3u+k]     = (1/sqrt3)*s*w1[u]*b[k] + (1/sqrt3)*a*w2[u]*v[k]
//                       + (1/sqrt6)*w4[u]*(v x b)[k]
//
// Thread mapping: 32 threads per edge, each owns 4 consecutive channels so
// every global load/store is an aligned float4.

__global__ __launch_bounds__(256) void tp_uvu_kernel(
    const float* __restrict__ x1,
    const float* __restrict__ x2,
    const float* __restrict__ w,
    float* __restrict__ out,
    int n_edges)
{
    const int tid = blockIdx.x * blockDim.x + threadIdx.x;
    const int z = tid >> 5;        // edge index
    const int g = tid & 31;        // channel group: channels 4g..4g+3
    if (z >= n_edges) return;

    constexpr float inv_sqrt3 = 0.57735026918962576f;
    constexpr float inv_sqrt6 = 0.40824829046386302f;

    // x2: broadcast across the 32 lanes of this edge (L1 serves it)
    const float4 x2v = *reinterpret_cast<const float4*>(x2 + (size_t)z * 4);
    const float a  = x2v.x;
    const float bx = x2v.y, by = x2v.z, bz = x2v.w;

    const float* x1row  = x1  + (size_t)z * 512;
    const float* wrow   = w   + (size_t)z * 640;
    float*       outrow = out + (size_t)z * 512;

    // scalar channels
    const float4 s4 = *reinterpret_cast<const float4*>(x1row + 4 * g);
    // vector channels: 12 consecutive floats per thread (16B-aligned)
    const float4 va = *reinterpret_cast<const float4*>(x1row + 128 + 12 * g);
    const float4 vb = *reinterpret_cast<const float4*>(x1row + 128 + 12 * g + 4);
    const float4 vc = *reinterpret_cast<const float4*>(x1row + 128 + 12 * g + 8);
    // 5 weight blocks
    const float4 w0 = *reinterpret_cast<const float4*>(wrow +   0 + 4 * g);
    const float4 w1 = *reinterpret_cast<const float4*>(wrow + 128 + 4 * g);
    const float4 w2 = *reinterpret_cast<const float4*>(wrow + 256 + 4 * g);
    const float4 w3 = *reinterpret_cast<const float4*>(wrow + 384 + 4 * g);
    const float4 w4 = *reinterpret_cast<const float4*>(wrow + 512 + 4 * g);

    const float s[4]  = {s4.x, s4.y, s4.z, s4.w};
    const float vv[12] = {va.x, va.y, va.z, va.w,
                          vb.x, vb.y, vb.z, vb.w,
                          vc.x, vc.y, vc.z, vc.w};
    const float W0[4] = {w0.x, w0.y, w0.z, w0.w};
    const float W1[4] = {w1.x, w1.y, w1.z, w1.w};
    const float W2[4] = {w2.x, w2.y, w2.z, w2.w};
    const float W3[4] = {w3.x, w3.y, w3.z, w3.w};
    const float W4[4] = {w4.x, w4.y, w4.z, w4.w};

    float os[4];
    float ov[12];
#pragma unroll
    for (int c = 0; c < 4; ++c) {
        const float vx = vv[3 * c + 0];
        const float vy = vv[3 * c + 1];
        const float vz = vv[3 * c + 2];
        const float dot = vx * bx + vy * by + vz * bz;
        os[c] = s[c] * a * W0[c] + inv_sqrt3 * dot * W3[c];

        // v x b
        const float cx = vy * bz - vz * by;
        const float cy = vz * bx - vx * bz;
        const float cz = vx * by - vy * bx;

        const float t1 = inv_sqrt3 * s[c] * W1[c];
        const float t2 = inv_sqrt3 * a   * W2[c];
        const float t4 = inv_sqrt6 * W4[c];
        ov[3 * c + 0] = t1 * bx + t2 * vx + t4 * cx;
        ov[3 * c + 1] = t1 * by + t2 * vy + t4 * cy;
        ov[3 * c + 2] = t1 * bz + t2 * vz + t4 * cz;
    }

    *reinterpret_cast<float4*>(outrow + 4 * g) =
        make_float4(os[0], os[1], os[2], os[3]);
    *reinterpret_cast<float4*>(outrow + 128 + 12 * g) =
        make_float4(ov[0], ov[1], ov[2], ov[3]);
    *reinterpret_cast<float4*>(outrow + 128 + 12 * g + 4) =
        make_float4(ov[4], ov[5], ov[6], ov[7]);
    *reinterpret_cast<float4*>(outrow + 128 + 12 * g + 8) =
        make_float4(ov[8], ov[9], ov[10], ov[11]);
}

extern "C" void kernel_launch(void* const* d_in, const int* in_sizes, int n_in,
                              void* d_out, int out_size, void* d_ws, size_t ws_size,
                              hipStream_t stream) {
    const float* x1 = (const float*)d_in[0];
    const float* x2 = (const float*)d_in[1];
    const float* w  = (const float*)d_in[2];
    float* out = (float*)d_out;

    const int n_edges = in_sizes[0] / 512;
    const long long total_threads = (long long)n_edges * 32;
    const int block = 256;
    const int grid = (int)((total_threads + block - 1) / block);

    tp_uvu_kernel<<<grid, block, 0, stream>>>(x1, x2, w, out, n_edges);
}